// Round 1
// baseline (607.807 us; speedup 1.0000x reference)
//
#include <hip/hip_runtime.h>
#include <hip/hip_bf16.h>
#include <stdint.h>

#define B_ 64
#define T_ 4096
#define H_ 256
#define U_ 256

typedef float f32x4 __attribute__((ext_vector_type(4)));
typedef short short8 __attribute__((ext_vector_type(8)));

__device__ __forceinline__ short bf16rne(float f) {
    uint32_t x = __builtin_bit_cast(uint32_t, f);
    return (short)((x + 0x7FFFu + ((x >> 16) & 1u)) >> 16);
}

__device__ __forceinline__ float fast_tanh(float x) {
    // tanh(x) = 1 - 2/(exp(2x)+1); correct limits at +/-inf
    float e = __expf(2.0f * x);
    return 1.0f - 2.0f * __builtin_amdgcn_rcpf(e + 1.0f);
}

// ---------------- W2 [h][u] fp32 -> transposed bf16 [u][k] with XOR swizzle --------------
__global__ __launch_bounds__(256) void k_convert_w2(const float* __restrict__ W2,
                                                    uint16_t* __restrict__ w2t) {
    int idx = blockIdx.x * 256 + threadIdx.x;   // 0..65535
    int h = idx >> 8;
    int u = idx & 255;
    float f = W2[idx];
    uint16_t bf = (uint16_t)bf16rne(f);
    uint32_t byte = (uint32_t)u * 512u + (((uint32_t)h * 2u) ^ (((uint32_t)(u & 7)) << 4));
    *(uint16_t*)((char*)w2t + byte) = bf;
}

// ---------------- qpc[b][u] = query[b]@W1 + b1[u] + b2[u] --------------------------------
__global__ __launch_bounds__(256) void k_qproj(const float* __restrict__ query,
                                               const float* __restrict__ W1,
                                               const float* __restrict__ b1,
                                               const float* __restrict__ b2,
                                               float* __restrict__ qpc) {
    __shared__ float qrow[H_];
    int b = blockIdx.x, u = threadIdx.x;
    qrow[u] = query[b * H_ + u];
    __syncthreads();
    float acc = b1[u] + b2[u];
#pragma unroll 8
    for (int h = 0; h < H_; ++h) acc += qrow[h] * W1[h * U_ + u];
    qpc[b * U_ + u] = acc;
}

// ---------------- main: score[b][t] = tanh(qpc + values@W2) . V --------------------------
#define TILES_PER_WG 4
__global__ __launch_bounds__(512) void k_scores(const float* __restrict__ values,
                                                const uint16_t* __restrict__ w2t,
                                                const float* __restrict__ qpc,
                                                const float* __restrict__ V,
                                                float* __restrict__ score) {
    extern __shared__ char smem[];
    char* w2b = smem;                           // 131072 B, bf16 [u][k] swizzled
    float* qpl = (float*)(smem + 131072);       // 256 f
    float* vl  = (float*)(smem + 132096);       // 256 f

    const int tid = threadIdx.x;
    const int wg = blockIdx.x;                  // 0..511
    const int b = wg >> 3;                      // 4 tiles/WG, 32 tiles per b

    // stage W2 (already swizzled in ws) linearly into LDS
    {
        const f32x4* src = (const f32x4*)w2t;
        f32x4* dst = (f32x4*)w2b;
#pragma unroll
        for (int i = 0; i < 16; ++i) dst[tid + i * 512] = src[tid + i * 512];
    }
    if (tid < 256) {
        qpl[tid] = qpc[b * U_ + tid];
        vl[tid] = V[tid];
    }
    __syncthreads();

    const int w = tid >> 6;     // wave 0..7
    const int l = tid & 63;
    const int c = l & 15;       // lane-in-16 (A row / B col / D col)
    const int g = l >> 4;       // group 0..3

    // hoist qpc/V values this lane needs (u = n*16 + c, fixed across tiles)
    float qv[16], vv[16];
#pragma unroll
    for (int n = 0; n < 16; ++n) {
        qv[n] = qpl[n * 16 + c];
        vv[n] = vl[n * 16 + c];
    }

    for (int it = 0; it < TILES_PER_WG; ++it) {
        const int tile = wg * TILES_PER_WG + it;
        const int t0 = (tile & 31) * 128;
        const int trow = t0 + w * 16 + c;
        const float* aptr = values + ((size_t)b * T_ + trow) * H_ + g * 8;

        f32x4 acc[16];
#pragma unroll
        for (int n = 0; n < 16; ++n) acc[n] = (f32x4)(0.0f);

#pragma unroll
        for (int ks = 0; ks < 8; ++ks) {
            f32x4 a0 = *(const f32x4*)(aptr + ks * 32);
            f32x4 a1 = *(const f32x4*)(aptr + ks * 32 + 4);
            short8 af;
            af[0] = bf16rne(a0[0]); af[1] = bf16rne(a0[1]);
            af[2] = bf16rne(a0[2]); af[3] = bf16rne(a0[3]);
            af[4] = bf16rne(a1[0]); af[5] = bf16rne(a1[1]);
            af[6] = bf16rne(a1[2]); af[7] = bf16rne(a1[3]);
            const int rb = ((ks * 64 + g * 16) ^ ((c & 7) << 4));
#pragma unroll
            for (int n = 0; n < 16; ++n) {
                short8 bfr = *(const short8*)(w2b + (n * 16 + c) * 512 + rb);
                acc[n] = __builtin_amdgcn_mfma_f32_16x16x32_bf16(af, bfr, acc[n], 0, 0, 0);
            }
        }

        // epilogue: tanh + dot with V, then reduce across the 16 "c" lanes
        float sc[4] = {0.f, 0.f, 0.f, 0.f};
#pragma unroll
        for (int n = 0; n < 16; ++n) {
#pragma unroll
            for (int r = 0; r < 4; ++r) {
                sc[r] += fast_tanh(acc[n][r] + qv[n]) * vv[n];
            }
        }
#pragma unroll
        for (int m = 1; m < 16; m <<= 1) {
#pragma unroll
            for (int r = 0; r < 4; ++r) sc[r] += __shfl_xor(sc[r], m, 64);
        }
        if (c == 0) {
            int rowbase = t0 + w * 16 + g * 4;
#pragma unroll
            for (int r = 0; r < 4; ++r) score[b * T_ + rowbase + r] = sc[r];
        }
    }
}

// ---------------- softmax over T per b ---------------------------------------------------
__global__ __launch_bounds__(256) void k_softmax(const float* __restrict__ score,
                                                 float* __restrict__ weights) {
    int b = blockIdx.x;
    __shared__ float redm[4];
    __shared__ float reds[4];
    const float* sp = score + (size_t)b * T_;
    float s[16];
    float mx = -1e30f;
#pragma unroll
    for (int i = 0; i < 16; ++i) {
        s[i] = sp[threadIdx.x + i * 256];
        mx = fmaxf(mx, s[i]);
    }
#pragma unroll
    for (int m = 1; m < 64; m <<= 1) mx = fmaxf(mx, __shfl_xor(mx, m, 64));
    int wv = threadIdx.x >> 6;
    if ((threadIdx.x & 63) == 0) redm[wv] = mx;
    __syncthreads();
    mx = fmaxf(fmaxf(redm[0], redm[1]), fmaxf(redm[2], redm[3]));
    float sum = 0.f;
#pragma unroll
    for (int i = 0; i < 16; ++i) {
        s[i] = __expf(s[i] - mx);
        sum += s[i];
    }
#pragma unroll
    for (int m = 1; m < 64; m <<= 1) sum += __shfl_xor(sum, m, 64);
    if ((threadIdx.x & 63) == 0) reds[wv] = sum;
    __syncthreads();
    sum = reds[0] + reds[1] + reds[2] + reds[3];
    float inv = 1.0f / sum;
#pragma unroll
    for (int i = 0; i < 16; ++i)
        weights[(size_t)b * T_ + threadIdx.x + i * 256] = s[i] * inv;
}

// ---------------- context partials: part[b][chunk][h] ------------------------------------
__global__ __launch_bounds__(256) void k_ctx_part(const float* __restrict__ values,
                                                  const float* __restrict__ weights,
                                                  float* __restrict__ part) {
    int b = blockIdx.x >> 4;
    int ch = blockIdx.x & 15;
    __shared__ float wl[256];
    int t0 = ch * 256;
    wl[threadIdx.x] = weights[(size_t)b * T_ + t0 + threadIdx.x];
    __syncthreads();
    const float* vp = values + ((size_t)b * T_ + t0) * H_ + threadIdx.x;
    float a0 = 0.f, a1 = 0.f, a2 = 0.f, a3 = 0.f;
#pragma unroll 2
    for (int t = 0; t < 256; t += 4) {
        a0 += wl[t + 0] * vp[(size_t)(t + 0) * H_];
        a1 += wl[t + 1] * vp[(size_t)(t + 1) * H_];
        a2 += wl[t + 2] * vp[(size_t)(t + 2) * H_];
        a3 += wl[t + 3] * vp[(size_t)(t + 3) * H_];
    }
    part[(size_t)blockIdx.x * 256 + threadIdx.x] = (a0 + a1) + (a2 + a3);
}

// ---------------- final reduce ------------------------------------------------------------
__global__ __launch_bounds__(256) void k_ctx_reduce(const float* __restrict__ part,
                                                    float* __restrict__ ctx) {
    int b = blockIdx.x;
    int h = threadIdx.x;
    float acc = 0.f;
#pragma unroll
    for (int c = 0; c < 16; ++c) acc += part[((size_t)b * 16 + c) * 256 + h];
    ctx[b * H_ + h] = acc;
}

extern "C" void kernel_launch(void* const* d_in, const int* in_sizes, int n_in,
                              void* d_out, int out_size, void* d_ws, size_t ws_size,
                              hipStream_t stream) {
    const float* query  = (const float*)d_in[0];
    const float* values = (const float*)d_in[1];
    const float* W1     = (const float*)d_in[2];
    const float* b1     = (const float*)d_in[3];
    const float* W2     = (const float*)d_in[4];
    const float* b2     = (const float*)d_in[5];
    const float* V      = (const float*)d_in[6];
    // d_in[7] = bV: softmax is shift-invariant, so bV does not affect outputs.

    float* out = (float*)d_out;
    float* ctx = out;                    // [B,H] = 16384 floats
    float* weights = out + B_ * H_;      // [B,T,1] = 262144 floats

    char* ws = (char*)d_ws;
    uint16_t* w2t  = (uint16_t*)ws;                              // 131072 B
    float* qpc     = (float*)(ws + 131072);                      // 65536 B
    float* scorebuf= (float*)(ws + 131072 + 65536);              // 1 MB
    float* part    = (float*)(ws + 131072 + 65536 + 1048576);    // 1 MB

    k_convert_w2<<<dim3(256), dim3(256), 0, stream>>>(W2, w2t);
    k_qproj<<<dim3(64), dim3(256), 0, stream>>>(query, W1, b1, b2, qpc);
    k_scores<<<dim3(512), dim3(512), 133120, stream>>>(values, w2t, qpc, V, scorebuf);
    k_softmax<<<dim3(64), dim3(256), 0, stream>>>(scorebuf, weights);
    k_ctx_part<<<dim3(B_ * 16), dim3(256), 0, stream>>>(values, weights, part);
    k_ctx_reduce<<<dim3(64), dim3(256), 0, stream>>>(part, ctx);
}

// Round 2
// 169.158 us; speedup vs baseline: 3.5931x; 3.5931x over previous
//
#include <hip/hip_runtime.h>
#include <stdint.h>

#define B_ 64
#define T_ 4096
#define H_ 256
#define U_ 256

typedef float f32x4 __attribute__((ext_vector_type(4)));
typedef short short8 __attribute__((ext_vector_type(8)));
typedef short short4v __attribute__((ext_vector_type(4)));

__device__ __forceinline__ short bf16rne(float f) {
    uint32_t x = __builtin_bit_cast(uint32_t, f);
    return (short)((x + 0x7FFFu + ((x >> 16) & 1u)) >> 16);
}

__device__ __forceinline__ float fast_tanh(float x) {
    // tanh(x) = 1 - 2/(exp(2x)+1); correct limits at +/-inf
    float e = __expf(2.0f * x);
    return 1.0f - 2.0f * __builtin_amdgcn_rcpf(e + 1.0f);
}

// ---------------- W2 [h][u] fp32 -> transposed bf16 w2t[u][h] (plain layout) -------------
__global__ __launch_bounds__(256) void k_convert_w2(const float* __restrict__ W2,
                                                    uint16_t* __restrict__ w2t) {
    int idx = blockIdx.x * 256 + threadIdx.x;   // 0..65535
    int h = idx >> 8;
    int u = idx & 255;
    w2t[u * 256 + h] = (uint16_t)bf16rne(W2[idx]);
}

// ---------------- qpc[b][u] = query[b]@W1 + b1[u] + b2[u] --------------------------------
__global__ __launch_bounds__(256) void k_qproj(const float* __restrict__ query,
                                               const float* __restrict__ W1,
                                               const float* __restrict__ b1,
                                               const float* __restrict__ b2,
                                               float* __restrict__ qpc) {
    __shared__ float qrow[H_];
    int b = blockIdx.x, u = threadIdx.x;
    qrow[u] = query[b * H_ + u];
    __syncthreads();
    float acc = b1[u] + b2[u];
#pragma unroll 8
    for (int h = 0; h < H_; ++h) acc += qrow[h] * W1[h * U_ + u];
    qpc[b * U_ + u] = acc;
}

// ---------------- main: score[b][t] = tanh(qpc + values@W2) . V --------------------------
// 1024 threads = 16 waves. Wave w owns u-strip [w*16, w*16+16), W2 frags in regs.
// Values tile: 32 rows x 256 k, bf16, XOR-swizzled in LDS, shared by all waves.
#define TR 32          // rows per tile
#define NT 16          // tiles per WG  -> 512 rows per WG
__global__ __launch_bounds__(1024, 4) void k_scores(const float* __restrict__ values,
                                                    const uint16_t* __restrict__ w2t,
                                                    const float* __restrict__ qpc,
                                                    const float* __restrict__ V,
                                                    float* __restrict__ score) {
    __shared__ char Ab[TR * 512];       // bf16 [32][256], byte ^= ((row&7)<<4)
    __shared__ float red[TR][17];       // per-row partials from 16 waves

    const int tid = threadIdx.x;
    const int wg = blockIdx.x;          // 0..511
    const int b = wg >> 3;
    const int chunk = (wg & 7) * (NT * TR);

    const int w = tid >> 6;             // wave 0..15
    const int l = tid & 63;
    const int c = l & 15;               // A row / B col within 16
    const int g = l >> 4;               // k-group 0..3
    const int u = w * 16 + c;           // this lane's u column

    // ---- B fragments held in registers for the whole kernel (32 VGPRs) ----
    short8 bfr[8];
#pragma unroll
    for (int ks = 0; ks < 8; ++ks)
        bfr[ks] = *(const short8*)(w2t + u * 256 + g * 8 + ks * 32);

    const float qv = qpc[b * U_ + u];
    const float vv = V[u];

    const float* vbase = values + (size_t)b * T_ * H_;

    // staging: thread (w,l) stages rows w and w+16, 16B (4 floats) at col l*4
    const int swz = (w & 7) << 4;       // same for rows w and w+16
    char* wr0 = Ab + (size_t)w * 512 + ((l * 8) ^ swz);
    char* wr1 = Ab + (size_t)(w + 16) * 512 + ((l * 8) ^ swz);

    // prologue: prefetch tile 0
    f32x4 pf0 = *(const f32x4*)(vbase + (size_t)(chunk + w) * H_ + l * 4);
    f32x4 pf1 = *(const f32x4*)(vbase + (size_t)(chunk + w + 16) * H_ + l * 4);

    for (int t = 0; t < NT; ++t) {
        const int t0 = chunk + t * TR;
        __syncthreads();                 // prev tile's A reads + red writes done
        // stage A(t) from prefetch regs
        {
            short4v s0, s1;
            s0[0] = bf16rne(pf0[0]); s0[1] = bf16rne(pf0[1]);
            s0[2] = bf16rne(pf0[2]); s0[3] = bf16rne(pf0[3]);
            s1[0] = bf16rne(pf1[0]); s1[1] = bf16rne(pf1[1]);
            s1[2] = bf16rne(pf1[2]); s1[3] = bf16rne(pf1[3]);
            *(short4v*)wr0 = s0;
            *(short4v*)wr1 = s1;
        }
        // reduce + store scores of previous tile (red written before barrier)
        if (t > 0 && tid < TR) {
            float s = 0.f;
#pragma unroll
            for (int j = 0; j < 16; ++j) s += red[tid][j];
            score[(size_t)b * T_ + (t0 - TR) + tid] = s;
        }
        // prefetch next tile (latency hides under compute below)
        if (t + 1 < NT) {
            pf0 = *(const f32x4*)(vbase + (size_t)(t0 + TR + w) * H_ + l * 4);
            pf1 = *(const f32x4*)(vbase + (size_t)(t0 + TR + w + 16) * H_ + l * 4);
        }
        __syncthreads();                 // A(t) ready

        f32x4 acc0 = (f32x4)(0.0f);
        f32x4 acc1 = (f32x4)(0.0f);
#pragma unroll
        for (int ks = 0; ks < 8; ++ks) {
            const int kb = (g * 16 + ks * 64) ^ ((c & 7) << 4);
            short8 a0 = *(const short8*)(Ab + (size_t)c * 512 + kb);
            short8 a1 = *(const short8*)(Ab + (size_t)(16 + c) * 512 + kb);
            acc0 = __builtin_amdgcn_mfma_f32_16x16x32_bf16(a0, bfr[ks], acc0, 0, 0, 0);
            acc1 = __builtin_amdgcn_mfma_f32_16x16x32_bf16(a1, bfr[ks], acc1, 0, 0, 0);
        }

        // epilogue: tanh + dot with V over this wave's 16 u's (lanes c=0..15)
        float sc[8];
#pragma unroll
        for (int r = 0; r < 4; ++r) {
            sc[r]     = fast_tanh(acc0[r] + qv) * vv;
            sc[4 + r] = fast_tanh(acc1[r] + qv) * vv;
        }
#pragma unroll
        for (int m = 1; m < 16; m <<= 1) {
#pragma unroll
            for (int r = 0; r < 8; ++r) sc[r] += __shfl_xor(sc[r], m, 64);
        }
        if (c == 0) {
#pragma unroll
            for (int r = 0; r < 4; ++r) {
                red[g * 4 + r][w] = sc[r];            // D row = g*4+r, tile rows 0..15
                red[16 + g * 4 + r][w] = sc[4 + r];   // tile rows 16..31
            }
        }
    }
    __syncthreads();
    if (tid < TR) {
        float s = 0.f;
#pragma unroll
        for (int j = 0; j < 16; ++j) s += red[tid][j];
        score[(size_t)b * T_ + chunk + (NT - 1) * TR + tid] = s;
    }
}

// ---------------- softmax over T per b ---------------------------------------------------
__global__ __launch_bounds__(256) void k_softmax(const float* __restrict__ score,
                                                 float* __restrict__ weights) {
    int b = blockIdx.x;
    __shared__ float redm[4];
    __shared__ float reds[4];
    const float* sp = score + (size_t)b * T_;
    float s[16];
    float mx = -1e30f;
#pragma unroll
    for (int i = 0; i < 16; ++i) {
        s[i] = sp[threadIdx.x + i * 256];
        mx = fmaxf(mx, s[i]);
    }
#pragma unroll
    for (int m = 1; m < 64; m <<= 1) mx = fmaxf(mx, __shfl_xor(mx, m, 64));
    int wv = threadIdx.x >> 6;
    if ((threadIdx.x & 63) == 0) redm[wv] = mx;
    __syncthreads();
    mx = fmaxf(fmaxf(redm[0], redm[1]), fmaxf(redm[2], redm[3]));
    float sum = 0.f;
#pragma unroll
    for (int i = 0; i < 16; ++i) {
        s[i] = __expf(s[i] - mx);
        sum += s[i];
    }
#pragma unroll
    for (int m = 1; m < 64; m <<= 1) sum += __shfl_xor(sum, m, 64);
    if ((threadIdx.x & 63) == 0) reds[wv] = sum;
    __syncthreads();
    sum = reds[0] + reds[1] + reds[2] + reds[3];
    float inv = 1.0f / sum;
#pragma unroll
    for (int i = 0; i < 16; ++i)
        weights[(size_t)b * T_ + threadIdx.x + i * 256] = s[i] * inv;
}

// ---------------- context partials: part[b][chunk][h] ------------------------------------
__global__ __launch_bounds__(256) void k_ctx_part(const float* __restrict__ values,
                                                  const float* __restrict__ weights,
                                                  float* __restrict__ part) {
    int b = blockIdx.x >> 4;
    int ch = blockIdx.x & 15;
    __shared__ float wl[256];
    int t0 = ch * 256;
    wl[threadIdx.x] = weights[(size_t)b * T_ + t0 + threadIdx.x];
    __syncthreads();
    const float* vp = values + ((size_t)b * T_ + t0) * H_ + threadIdx.x;
    float a0 = 0.f, a1 = 0.f, a2 = 0.f, a3 = 0.f;
#pragma unroll 2
    for (int t = 0; t < 256; t += 4) {
        a0 += wl[t + 0] * vp[(size_t)(t + 0) * H_];
        a1 += wl[t + 1] * vp[(size_t)(t + 1) * H_];
        a2 += wl[t + 2] * vp[(size_t)(t + 2) * H_];
        a3 += wl[t + 3] * vp[(size_t)(t + 3) * H_];
    }
    part[(size_t)blockIdx.x * 256 + threadIdx.x] = (a0 + a1) + (a2 + a3);
}

// ---------------- final reduce ------------------------------------------------------------
__global__ __launch_bounds__(256) void k_ctx_reduce(const float* __restrict__ part,
                                                    float* __restrict__ ctx) {
    int b = blockIdx.x;
    int h = threadIdx.x;
    float acc = 0.f;
#pragma unroll
    for (int ci = 0; ci < 16; ++ci) acc += part[((size_t)b * 16 + ci) * 256 + h];
    ctx[b * H_ + h] = acc;
}

extern "C" void kernel_launch(void* const* d_in, const int* in_sizes, int n_in,
                              void* d_out, int out_size, void* d_ws, size_t ws_size,
                              hipStream_t stream) {
    const float* query  = (const float*)d_in[0];
    const float* values = (const float*)d_in[1];
    const float* W1     = (const float*)d_in[2];
    const float* b1     = (const float*)d_in[3];
    const float* W2     = (const float*)d_in[4];
    const float* b2     = (const float*)d_in[5];
    const float* V      = (const float*)d_in[6];
    // d_in[7] = bV: softmax is shift-invariant -> no effect on outputs.

    float* out = (float*)d_out;
    float* ctx = out;                    // [B,H] = 16384 floats
    float* weights = out + B_ * H_;      // [B,T,1] = 262144 floats

    char* ws = (char*)d_ws;
    uint16_t* w2t   = (uint16_t*)ws;                             // 131072 B
    float* qpc      = (float*)(ws + 131072);                     // 65536 B
    float* scorebuf = (float*)(ws + 131072 + 65536);             // 1 MB
    float* part     = (float*)(ws + 131072 + 65536 + 1048576);   // 1 MB

    k_convert_w2<<<dim3(256), dim3(256), 0, stream>>>(W2, w2t);
    k_qproj<<<dim3(64), dim3(256), 0, stream>>>(query, W1, b1, b2, qpc);
    k_scores<<<dim3(512), dim3(1024), 0, stream>>>(values, w2t, qpc, V, scorebuf);
    k_softmax<<<dim3(64), dim3(256), 0, stream>>>(scorebuf, weights);
    k_ctx_part<<<dim3(B_ * 16), dim3(256), 0, stream>>>(values, weights, part);
    k_ctx_reduce<<<dim3(64), dim3(256), 0, stream>>>(part, ctx);
}

// Round 3
// 166.136 us; speedup vs baseline: 3.6585x; 1.0182x over previous
//
#include <hip/hip_runtime.h>
#include <stdint.h>

#define B_ 64
#define T_ 4096
#define H_ 256
#define U_ 256

typedef float f32x4 __attribute__((ext_vector_type(4)));
typedef short short8 __attribute__((ext_vector_type(8)));
typedef short short4v __attribute__((ext_vector_type(4)));

__device__ __forceinline__ short bf16rne(float f) {
    uint32_t x = __builtin_bit_cast(uint32_t, f);
    return (short)((x + 0x7FFFu + ((x >> 16) & 1u)) >> 16);
}

__device__ __forceinline__ float fast_tanh(float x) {
    float e = __expf(2.0f * x);
    return 1.0f - 2.0f * __builtin_amdgcn_rcpf(e + 1.0f);
}

// ---- fused prep: blocks 0-255 convert W2 -> w2t[u][h] bf16; blocks 256-319 qproj ----
__global__ __launch_bounds__(256) void k_prep(const float* __restrict__ W2,
                                              uint16_t* __restrict__ w2t,
                                              const float* __restrict__ query,
                                              const float* __restrict__ W1,
                                              const float* __restrict__ b1,
                                              const float* __restrict__ b2,
                                              float* __restrict__ qpc) {
    if (blockIdx.x < 256) {
        int idx = blockIdx.x * 256 + threadIdx.x;
        int h = idx >> 8;
        int u = idx & 255;
        w2t[u * 256 + h] = (uint16_t)bf16rne(W2[idx]);
    } else {
        __shared__ float qrow[H_];
        int b = blockIdx.x - 256, u = threadIdx.x;
        qrow[u] = query[b * H_ + u];
        __syncthreads();
        float acc = b1[u] + b2[u];
#pragma unroll 8
        for (int h = 0; h < H_; ++h) acc += qrow[h] * W1[h * U_ + u];
        qpc[b * U_ + u] = acc;
    }
}

// ---------------- main: score[b][t] = tanh(qpc + values@W2) . V --------------------------
// Swapped MFMA: D[u,t] = W2^T(u,h) x values^T(h,t).  512 thr = 8 waves, wave owns 32 u
// (2 strips of 16).  A (W2) frags in regs; B (values tile, 32 t-rows bf16, XOR-swizzled)
// in LDS.  D: col(lane&15)=t, row(g*4+r)=u -> V-dot is in-lane + 2 shfl_xor.
#define TR 32          // t-rows per tile
#define NT 8           // tiles per WG  -> 256 rows per WG
__global__ __launch_bounds__(512, 4) void k_scores(const float* __restrict__ values,
                                                   const uint16_t* __restrict__ w2t,
                                                   const float* __restrict__ qpc,
                                                   const float* __restrict__ V,
                                                   float* __restrict__ score) {
    __shared__ char Ab[TR * 512];       // bf16 [32][256], byte ^= ((row&7)<<4)
    __shared__ float red[TR][9];        // per-row partials from 8 waves

    const int tid = threadIdx.x;
    const int wg = blockIdx.x;          // 0..1023
    const int b = wg >> 4;
    const int chunk = (wg & 15) * (NT * TR);

    const int w = tid >> 6;             // wave 0..7
    const int l = tid & 63;
    const int c = l & 15;               // A row (u in strip) / B col (t in subtile)
    const int g = l >> 4;               // k-group 0..3

    // ---- A fragments (W2) in regs for whole kernel: 2 strips x 8 ks ----
    short8 afr[2][8];
#pragma unroll
    for (int s = 0; s < 2; ++s) {
        const uint16_t* ap = w2t + (size_t)(w * 32 + s * 16 + c) * 256 + g * 8;
#pragma unroll
        for (int ks = 0; ks < 8; ++ks) afr[s][ks] = *(const short8*)(ap + ks * 32);
    }
    // per-lane qpc/V for the 8 u's this lane's D covers: u = w*32 + s*16 + g*4 + r
    float qv[2][4], vv[2][4];
#pragma unroll
    for (int s = 0; s < 2; ++s)
#pragma unroll
        for (int r = 0; r < 4; ++r) {
            int u = w * 32 + s * 16 + g * 4 + r;
            qv[s][r] = qpc[b * U_ + u];
            vv[s][r] = V[u];
        }

    const float* vbase = values + (size_t)b * T_ * H_;

    // staging: thread stages row = tid>>4, two 16B bf16 chunks at cols q*8 and q*8+128
    const int srow = tid >> 4;
    const int q = tid & 15;
    const int sswz = (srow & 7) << 4;
    char* wr0 = Ab + srow * 512 + ((q * 16) ^ sswz);
    char* wr1 = Ab + srow * 512 + ((q * 16 + 256) ^ sswz);
    const float* sbase = vbase + (size_t)srow * H_ + q * 8;

    // prologue: prefetch tile 0
    f32x4 p0 = *(const f32x4*)(sbase + (size_t)chunk * H_);
    f32x4 p1 = *(const f32x4*)(sbase + (size_t)chunk * H_ + 4);
    f32x4 p2 = *(const f32x4*)(sbase + (size_t)chunk * H_ + 128);
    f32x4 p3 = *(const f32x4*)(sbase + (size_t)chunk * H_ + 132);

    for (int t = 0; t < NT; ++t) {
        const int t0 = chunk + t * TR;
        __syncthreads();                 // prev tile's B reads + red writes done
        {   // stage tile t from prefetch regs
            short8 s0, s1;
            s0[0] = bf16rne(p0[0]); s0[1] = bf16rne(p0[1]);
            s0[2] = bf16rne(p0[2]); s0[3] = bf16rne(p0[3]);
            s0[4] = bf16rne(p1[0]); s0[5] = bf16rne(p1[1]);
            s0[6] = bf16rne(p1[2]); s0[7] = bf16rne(p1[3]);
            s1[0] = bf16rne(p2[0]); s1[1] = bf16rne(p2[1]);
            s1[2] = bf16rne(p2[2]); s1[3] = bf16rne(p2[3]);
            s1[4] = bf16rne(p3[0]); s1[5] = bf16rne(p3[1]);
            s1[6] = bf16rne(p3[2]); s1[7] = bf16rne(p3[3]);
            *(short8*)wr0 = s0;
            *(short8*)wr1 = s1;
        }
        // reduce + store scores of previous tile
        if (t > 0 && tid < TR) {
            float s = 0.f;
#pragma unroll
            for (int j = 0; j < 8; ++j) s += red[tid][j];
            score[(size_t)b * T_ + (t0 - TR) + tid] = s;
        }
        // prefetch next tile
        if (t + 1 < NT) {
            const float* nb = sbase + (size_t)(t0 + TR) * H_;
            p0 = *(const f32x4*)(nb);
            p1 = *(const f32x4*)(nb + 4);
            p2 = *(const f32x4*)(nb + 128);
            p3 = *(const f32x4*)(nb + 132);
        }
        __syncthreads();                 // tile t staged

#pragma unroll
        for (int sub = 0; sub < 2; ++sub) {
            const char* rp = Ab + (sub * 16 + c) * 512;
            const int swz = (c & 7) << 4;
            f32x4 acc0 = (f32x4)(0.0f);
            f32x4 acc1 = (f32x4)(0.0f);
#pragma unroll
            for (int ks = 0; ks < 8; ++ks) {
                short8 bf = *(const short8*)(rp + ((ks * 64 + g * 16) ^ swz));
                acc0 = __builtin_amdgcn_mfma_f32_16x16x32_bf16(afr[0][ks], bf, acc0, 0, 0, 0);
                acc1 = __builtin_amdgcn_mfma_f32_16x16x32_bf16(afr[1][ks], bf, acc1, 0, 0, 0);
            }
            // epilogue: tanh + V-dot over this wave's 32 u's (in-lane + cross-g)
            float p = 0.f;
#pragma unroll
            for (int r = 0; r < 4; ++r) {
                p += fast_tanh(acc0[r] + qv[0][r]) * vv[0][r];
                p += fast_tanh(acc1[r] + qv[1][r]) * vv[1][r];
            }
            p += __shfl_xor(p, 16, 64);
            p += __shfl_xor(p, 32, 64);
            if (g == 0) red[sub * 16 + c][w] = p;
        }
    }
    __syncthreads();
    if (tid < TR) {
        float s = 0.f;
#pragma unroll
        for (int j = 0; j < 8; ++j) s += red[tid][j];
        score[(size_t)b * T_ + chunk + (NT - 1) * TR + tid] = s;
    }
}

// ---------------- softmax over T per b ---------------------------------------------------
__global__ __launch_bounds__(256) void k_softmax(const float* __restrict__ score,
                                                 float* __restrict__ weights) {
    int b = blockIdx.x;
    __shared__ float redm[4];
    __shared__ float reds[4];
    const float* sp = score + (size_t)b * T_;
    float s[16];
    float mx = -1e30f;
#pragma unroll
    for (int i = 0; i < 16; ++i) {
        s[i] = sp[threadIdx.x + i * 256];
        mx = fmaxf(mx, s[i]);
    }
#pragma unroll
    for (int m = 1; m < 64; m <<= 1) mx = fmaxf(mx, __shfl_xor(mx, m, 64));
    int wv = threadIdx.x >> 6;
    if ((threadIdx.x & 63) == 0) redm[wv] = mx;
    __syncthreads();
    mx = fmaxf(fmaxf(redm[0], redm[1]), fmaxf(redm[2], redm[3]));
    float sum = 0.f;
#pragma unroll
    for (int i = 0; i < 16; ++i) {
        s[i] = __expf(s[i] - mx);
        sum += s[i];
    }
#pragma unroll
    for (int m = 1; m < 64; m <<= 1) sum += __shfl_xor(sum, m, 64);
    if ((threadIdx.x & 63) == 0) reds[wv] = sum;
    __syncthreads();
    sum = reds[0] + reds[1] + reds[2] + reds[3];
    float inv = 1.0f / sum;
#pragma unroll
    for (int i = 0; i < 16; ++i)
        weights[(size_t)b * T_ + threadIdx.x + i * 256] = s[i] * inv;
}

// ---------------- context partials (REVERSED order for L3 reuse) -------------------------
__global__ __launch_bounds__(256) void k_ctx_part(const float* __restrict__ values,
                                                  const float* __restrict__ weights,
                                                  float* __restrict__ part) {
    int bid = (B_ * 16 - 1) - blockIdx.x;   // descending: last-streamed values first
    int b = bid >> 4;
    int ch = bid & 15;
    __shared__ float wl[256];
    int t0 = ch * 256;
    wl[threadIdx.x] = weights[(size_t)b * T_ + t0 + threadIdx.x];
    __syncthreads();
    const float* vp = values + ((size_t)b * T_ + t0) * H_ + threadIdx.x;
    float a0 = 0.f, a1 = 0.f, a2 = 0.f, a3 = 0.f;
#pragma unroll 2
    for (int t = 0; t < 256; t += 4) {
        a0 += wl[t + 0] * vp[(size_t)(t + 0) * H_];
        a1 += wl[t + 1] * vp[(size_t)(t + 1) * H_];
        a2 += wl[t + 2] * vp[(size_t)(t + 2) * H_];
        a3 += wl[t + 3] * vp[(size_t)(t + 3) * H_];
    }
    part[(size_t)bid * 256 + threadIdx.x] = (a0 + a1) + (a2 + a3);
}

// ---------------- final reduce ------------------------------------------------------------
__global__ __launch_bounds__(256) void k_ctx_reduce(const float* __restrict__ part,
                                                    float* __restrict__ ctx) {
    int b = blockIdx.x;
    int h = threadIdx.x;
    float acc = 0.f;
#pragma unroll
    for (int ci = 0; ci < 16; ++ci) acc += part[((size_t)b * 16 + ci) * 256 + h];
    ctx[b * H_ + h] = acc;
}

extern "C" void kernel_launch(void* const* d_in, const int* in_sizes, int n_in,
                              void* d_out, int out_size, void* d_ws, size_t ws_size,
                              hipStream_t stream) {
    const float* query  = (const float*)d_in[0];
    const float* values = (const float*)d_in[1];
    const float* W1     = (const float*)d_in[2];
    const float* b1     = (const float*)d_in[3];
    const float* W2     = (const float*)d_in[4];
    const float* b2     = (const float*)d_in[5];
    const float* V      = (const float*)d_in[6];
    // d_in[7] = bV: softmax is shift-invariant -> no effect on outputs.

    float* out = (float*)d_out;
    float* ctx = out;                    // [B,H]
    float* weights = out + B_ * H_;      // [B,T,1]

    char* ws = (char*)d_ws;
    uint16_t* w2t   = (uint16_t*)ws;                             // 131072 B
    float* qpc      = (float*)(ws + 131072);                     // 65536 B
    float* scorebuf = (float*)(ws + 131072 + 65536);             // 1 MB
    float* part     = (float*)(ws + 131072 + 65536 + 1048576);   // 1 MB

    k_prep<<<dim3(320), dim3(256), 0, stream>>>(W2, w2t, query, W1, b1, b2, qpc);
    k_scores<<<dim3(1024), dim3(512), 0, stream>>>(values, w2t, qpc, V, scorebuf);
    k_softmax<<<dim3(64), dim3(256), 0, stream>>>(scorebuf, weights);
    k_ctx_part<<<dim3(B_ * 16), dim3(256), 0, stream>>>(values, weights, part);
    k_ctx_reduce<<<dim3(64), dim3(256), 0, stream>>>(part, ctx);
}

// Round 4
// 93.425 us; speedup vs baseline: 6.5058x; 1.7783x over previous
//
#include <hip/hip_runtime.h>
#include <stdint.h>

#define B_ 64
#define T_ 4096
#define H_ 256
#define U_ 256

typedef float f32x4 __attribute__((ext_vector_type(4)));
typedef short short8 __attribute__((ext_vector_type(8)));

__device__ __forceinline__ short bf16rne(float f) {
    uint32_t x = __builtin_bit_cast(uint32_t, f);
    return (short)((x + 0x7FFFu + ((x >> 16) & 1u)) >> 16);
}

__device__ __forceinline__ float fast_tanh(float x) {
    float e = __expf(2.0f * x);
    return 1.0f - 2.0f * __builtin_amdgcn_rcpf(e + 1.0f);
}

// ---- fused prep: blocks 0-255 convert W2 -> w2t[u][h] bf16; blocks 256-319 qproj ----
__global__ __launch_bounds__(256) void k_prep(const float* __restrict__ W2,
                                              uint16_t* __restrict__ w2t,
                                              const float* __restrict__ query,
                                              const float* __restrict__ W1,
                                              const float* __restrict__ b1,
                                              const float* __restrict__ b2,
                                              float* __restrict__ qpc) {
    if (blockIdx.x < 256) {
        int idx = blockIdx.x * 256 + threadIdx.x;
        int h = idx >> 8;
        int u = idx & 255;
        w2t[u * 256 + h] = (uint16_t)bf16rne(W2[idx]);
    } else {
        __shared__ float qrow[H_];
        int b = blockIdx.x - 256, u = threadIdx.x;
        qrow[u] = query[b * H_ + u];
        __syncthreads();
        float acc = b1[u] + b2[u];
#pragma unroll 8
        for (int h = 0; h < H_; ++h) acc += qrow[h] * W1[h * U_ + u];
        qpc[b * U_ + u] = acc;
    }
}

// ---------------- fused main ----------------
// Per WG (512 thr, 8 waves, 256 t-rows): scores via swapped MFMA D[u,t] (W2 frags in
// regs, values tile bf16 XOR-swizzled in LDS), then unnormalized-softmax context
// accumulation from the fp32 prefetch registers (values read ONCE from HBM).
// Unnormalized exp is safe: |score| <= sum|V_u| ~ 13 -> exp <= 4e5, fp32-safe.
#define TR 32          // t-rows per tile
#define NT 8           // tiles per WG  -> 256 rows per WG
__global__ __launch_bounds__(512, 2) void k_main(const float* __restrict__ values,
                                                 const uint16_t* __restrict__ w2t,
                                                 const float* __restrict__ qpc,
                                                 const float* __restrict__ V,
                                                 float* __restrict__ score,
                                                 float* __restrict__ part_O,
                                                 float* __restrict__ part_s) {
    __shared__ __align__(16) char Ab[TR * 512];   // bf16 [32][256], byte ^= ((row&7)<<4)
    __shared__ float red[TR][9];                  // per-row partials from 8 waves
    __shared__ float Ored[TR][16][16];            // per-thread context partials (32 KB)
    __shared__ float sred[TR];

    const int tid = threadIdx.x;
    const int wg = blockIdx.x;          // 0..1023
    const int b = wg >> 4;
    const int chunk = (wg & 15) * (NT * TR);

    const int w = tid >> 6;             // wave 0..7
    const int l = tid & 63;
    const int c = l & 15;
    const int g = l >> 4;

    // A fragments (W2) in regs for whole kernel: 2 strips x 8 ks  (64 VGPR)
    short8 afr[2][8];
#pragma unroll
    for (int s = 0; s < 2; ++s) {
        const uint16_t* ap = w2t + (size_t)(w * 32 + s * 16 + c) * 256 + g * 8;
#pragma unroll
        for (int ks = 0; ks < 8; ++ks) afr[s][ks] = *(const short8*)(ap + ks * 32);
    }
    float qv[2][4], vv[2][4];
#pragma unroll
    for (int s = 0; s < 2; ++s)
#pragma unroll
        for (int r = 0; r < 4; ++r) {
            int u = w * 32 + s * 16 + g * 4 + r;
            qv[s][r] = qpc[b * U_ + u];
            vv[s][r] = V[u];
        }

    const float* vbase = values + (size_t)b * T_ * H_;
    const int srow = tid >> 4;          // 0..31: row this thread stages/consumes
    const int q = tid & 15;             // 16B chunk within row
    const int sswz = (srow & 7) << 4;
    char* wr0 = Ab + srow * 512 + ((q * 16) ^ sswz);
    char* wr1 = Ab + srow * 512 + ((q * 16 + 256) ^ sswz);
    const float* sbase = vbase + (size_t)srow * H_ + q * 8;

    // rotating fp32 value tiles, prefetch distance 2 (period-3 static slots)
    f32x4 vt[3][4];
    float Oacc[16];
#pragma unroll
    for (int j = 0; j < 16; ++j) Oacc[j] = 0.f;
    float sacc = 0.f;

    {   // prologue: tiles 0 and 1
        const float* nb0 = sbase + (size_t)chunk * H_;
        vt[0][0] = *(const f32x4*)(nb0);       vt[0][1] = *(const f32x4*)(nb0 + 4);
        vt[0][2] = *(const f32x4*)(nb0 + 128); vt[0][3] = *(const f32x4*)(nb0 + 132);
        const float* nb1 = sbase + (size_t)(chunk + TR) * H_;
        vt[1][0] = *(const f32x4*)(nb1);       vt[1][1] = *(const f32x4*)(nb1 + 4);
        vt[1][2] = *(const f32x4*)(nb1 + 128); vt[1][3] = *(const f32x4*)(nb1 + 132);
    }

#pragma unroll
    for (int t = 0; t < NT; ++t) {
        const int cs = t % 3;            // current tile slot (stage now)
        const int os = (t + 2) % 3;      // == (t-1)%3: old slot (consume), then load t+2
        __syncthreads();                 // red(t-1) ready; Ab free
        {   // stage tile t: fp32 regs -> bf16 swizzled LDS
            short8 s0, s1;
            s0[0] = bf16rne(vt[cs][0][0]); s0[1] = bf16rne(vt[cs][0][1]);
            s0[2] = bf16rne(vt[cs][0][2]); s0[3] = bf16rne(vt[cs][0][3]);
            s0[4] = bf16rne(vt[cs][1][0]); s0[5] = bf16rne(vt[cs][1][1]);
            s0[6] = bf16rne(vt[cs][1][2]); s0[7] = bf16rne(vt[cs][1][3]);
            s1[0] = bf16rne(vt[cs][2][0]); s1[1] = bf16rne(vt[cs][2][1]);
            s1[2] = bf16rne(vt[cs][2][2]); s1[3] = bf16rne(vt[cs][2][3]);
            s1[4] = bf16rne(vt[cs][3][0]); s1[5] = bf16rne(vt[cs][3][1]);
            s1[6] = bf16rne(vt[cs][3][2]); s1[7] = bf16rne(vt[cs][3][3]);
            *(short8*)wr0 = s0;
            *(short8*)wr1 = s1;
        }
        // consume tile t-1: scores -> weights -> context accumulation (fp32 regs)
        if (t > 0) {
            float ssum = 0.f;
#pragma unroll
            for (int j = 0; j < 8; ++j) ssum += red[srow][j];
            float wgt = __expf(ssum);
            if (q == 0) {
                sacc += wgt;
                score[(size_t)b * T_ + chunk + (t - 1) * TR + srow] = ssum;
            }
#pragma unroll
            for (int vj = 0; vj < 4; ++vj)
#pragma unroll
                for (int j = 0; j < 4; ++j)
                    Oacc[vj * 4 + j] += wgt * vt[os][vj][j];
        }
        // prefetch tile t+2 into the just-freed old slot
        if (t + 2 < NT) {
            const float* nb = sbase + (size_t)(chunk + (t + 2) * TR) * H_;
            vt[os][0] = *(const f32x4*)(nb);       vt[os][1] = *(const f32x4*)(nb + 4);
            vt[os][2] = *(const f32x4*)(nb + 128); vt[os][3] = *(const f32x4*)(nb + 132);
        }
        __syncthreads();                 // Ab(t) staged
        // MFMA phase
#pragma unroll
        for (int sub = 0; sub < 2; ++sub) {
            const char* rp = Ab + (sub * 16 + c) * 512;
            const int swz = (c & 7) << 4;
            f32x4 acc0 = (f32x4)(0.0f);
            f32x4 acc1 = (f32x4)(0.0f);
#pragma unroll
            for (int ks = 0; ks < 8; ++ks) {
                short8 bf = *(const short8*)(rp + ((ks * 64 + g * 16) ^ swz));
                acc0 = __builtin_amdgcn_mfma_f32_16x16x32_bf16(afr[0][ks], bf, acc0, 0, 0, 0);
                acc1 = __builtin_amdgcn_mfma_f32_16x16x32_bf16(afr[1][ks], bf, acc1, 0, 0, 0);
            }
            float p = 0.f;
#pragma unroll
            for (int r = 0; r < 4; ++r) {
                p += fast_tanh(acc0[r] + qv[0][r]) * vv[0][r];
                p += fast_tanh(acc1[r] + qv[1][r]) * vv[1][r];
            }
            p += __shfl_xor(p, 16, 64);
            p += __shfl_xor(p, 32, 64);
            if (g == 0) red[sub * 16 + c][w] = p;
        }
    }
    __syncthreads();
    {   // final consume: tile NT-1 (fp32 still in slot (NT-1)%3)
        const int fs = (NT - 1) % 3;
        float ssum = 0.f;
#pragma unroll
        for (int j = 0; j < 8; ++j) ssum += red[srow][j];
        float wgt = __expf(ssum);
        if (q == 0) {
            sacc += wgt;
            score[(size_t)b * T_ + chunk + (NT - 1) * TR + srow] = ssum;
        }
#pragma unroll
        for (int vj = 0; vj < 4; ++vj)
#pragma unroll
            for (int j = 0; j < 4; ++j)
                Oacc[vj * 4 + j] += wgt * vt[fs][vj][j];
    }
    // reduce per-thread context partials across the 32 rows
#pragma unroll
    for (int j = 0; j < 16; ++j) Ored[srow][q][j] = Oacc[j];
    if (q == 0) sred[srow] = sacc;
    __syncthreads();
    if (tid < 256) {
        int col = tid;
        int qq, jj;
        if (col < 128) { qq = col >> 3; jj = col & 7; }
        else           { qq = (col - 128) >> 3; jj = 8 + (col & 7); }
        float o = 0.f;
#pragma unroll
        for (int s = 0; s < TR; ++s) o += Ored[s][qq][jj];
        part_O[(size_t)wg * 256 + col] = o;
    }
    if (tid == 0) {
        float sb = 0.f;
#pragma unroll
        for (int s = 0; s < TR; ++s) sb += sred[s];
        part_s[wg] = sb;
    }
}

// ---------------- finish: reduce partials, write ctx + normalized weights ----------------
__global__ __launch_bounds__(256) void k_fin(const float* __restrict__ part_O,
                                             const float* __restrict__ part_s,
                                             const float* __restrict__ score,
                                             float* __restrict__ ctx,
                                             float* __restrict__ weights) {
    int b = blockIdx.x;
    int col = threadIdx.x;
    float sb = 0.f;
#pragma unroll
    for (int ch = 0; ch < 16; ++ch) sb += part_s[b * 16 + ch];
    float o = 0.f;
#pragma unroll
    for (int ch = 0; ch < 16; ++ch) o += part_O[(size_t)(b * 16 + ch) * 256 + col];
    float inv = 1.0f / sb;
    ctx[b * H_ + col] = o * inv;
#pragma unroll
    for (int i = 0; i < 16; ++i) {
        float s = score[(size_t)b * T_ + col + i * 256];
        weights[(size_t)b * T_ + col + i * 256] = __expf(s) * inv;
    }
}

extern "C" void kernel_launch(void* const* d_in, const int* in_sizes, int n_in,
                              void* d_out, int out_size, void* d_ws, size_t ws_size,
                              hipStream_t stream) {
    const float* query  = (const float*)d_in[0];
    const float* values = (const float*)d_in[1];
    const float* W1     = (const float*)d_in[2];
    const float* b1     = (const float*)d_in[3];
    const float* W2     = (const float*)d_in[4];
    const float* b2     = (const float*)d_in[5];
    const float* V      = (const float*)d_in[6];
    // d_in[7] = bV: softmax is shift-invariant -> no effect on outputs.

    float* out = (float*)d_out;
    float* ctx = out;                    // [B,H]
    float* weights = out + B_ * H_;      // [B,T,1]

    char* ws = (char*)d_ws;
    uint16_t* w2t   = (uint16_t*)ws;                               // 128 KB
    float* qpc      = (float*)(ws + 131072);                       // 64 KB
    float* scorebuf = (float*)(ws + 131072 + 65536);               // 1 MB
    float* part_O   = (float*)(ws + 131072 + 65536 + 1048576);     // 1 MB
    float* part_s   = (float*)(ws + 131072 + 65536 + 2097152);     // 4 KB

    k_prep<<<dim3(320), dim3(256), 0, stream>>>(W2, w2t, query, W1, b1, b2, qpc);
    k_main<<<dim3(1024), dim3(512), 0, stream>>>(values, w2t, qpc, V, scorebuf,
                                                 part_O, part_s);
    k_fin<<<dim3(64), dim3(256), 0, stream>>>(part_O, part_s, scorebuf, ctx, weights);
}